// Round 3
// baseline (155.218 us; speedup 1.0000x reference)
//
#include <hip/hip_runtime.h>

#define BS 4096
#define LL 512
#define NW 8                 // waves per block
#define START_TAG 1
#define END_TAG 2
#define BIAS 4.5f            // per-step 2^-BIAS scaling, restored exactly in log2
#define L2E 1.44269504f

typedef float f32x4 __attribute__((ext_vector_type(4)));
typedef short s16x4 __attribute__((ext_vector_type(4)));
union BF4 { unsigned u[2]; s16x4 s; };

__device__ __forceinline__ unsigned cvt_pk_bf16(float lo, float hi) {
    unsigned r;
    asm("v_cvt_pk_bf16_f32 %0, %1, %2" : "=v"(r) : "v"(lo), "v"(hi));
    return r;
}

// One wave = one batch's full 512-step chain in exp space:
//   alpha' = diag(e^em * 2^-BIAS) * E^T * alpha,  E = exp(transition)
// Running 16x16 product via one v_mfma_f32_16x16x16_bf16 per step
// (D layout == B layout -> in-lane cvt_pk repack). Power-of-2 renorm /32 steps.
// NO workspace usage at all; result accumulated into out[0] by atomicAdd.
__global__ __launch_bounds__(NW * 64) void crf_fused(
    const float* __restrict__ em, const int* __restrict__ tg,
    const float* __restrict__ mk, const float* __restrict__ tr,
    float* __restrict__ out)
{
    const int wv   = threadIdx.x >> 6;
    const int b    = blockIdx.x * NW + wv;
    const int lane = threadIdx.x & 63;
    const int j    = lane & 15;   // matrix col for B/D, row for A
    const int q    = lane >> 4;   // k-block

    // ---- tags dtype detection: u64 view values <16 for all 16 words => int64
    int is64 = 1;
    {
        const unsigned long long* t64 = (const unsigned long long*)tg;
        for (int i = 0; i < 16; ++i) is64 &= (t64[i] < 16ull) ? 1 : 0;
    }

    // ---- static per-lane factors: Ef[i] = E[q*4+i][j], Te[i] = tr[q*4+i][END]
    float Ef[4], Te[4];
#pragma unroll
    for (int i = 0; i < 4; ++i) {
        Ef[i] = expf(tr[(q * 4 + i) * 16 + j]);   // exp(-1000) -> exact 0
        Te[i] = tr[(q * 4 + i) * 16 + END_TAG];
    }

    // ---- B (bf16) and D (f32) start as identity
    unsigned b01 = ((q*4+0 == j) ? 0x3F80u : 0u) | (((q*4+1 == j) ? 0x3F80u : 0u) << 16);
    unsigned b23 = ((q*4+2 == j) ? 0x3F80u : 0u) | (((q*4+3 == j) ? 0x3F80u : 0u) << 16);
    f32x4 d;
#pragma unroll
    for (int i = 0; i < 4; ++i) d[i] = (q*4+i == j) ? 1.f : 0.f;

    const long base = (long)b * LL;
    const float* emp = em + (base << 4) + lane;

    float sc = 0.f, cnt = 0.f, e2f = 0.f;

    for (int g = 0; g < LL; g += 4) {
        const int   t    = g + q;               // this lane-group's step
        const long  ti   = base + t;
        const float em4  = emp[(long)g << 4];   // em[b][t][j], 256B coalesced
        const float mk4  = mk[ti];
        const int   tcur = tg[is64 ? (ti << 1) : ti];
        const long  tip  = ti - (t > 0 ? 1 : 0);
        const int   tpl  = tg[is64 ? (tip << 1) : tip];
        const int   tprev = (t == 0) ? START_TAG : tpl;
        const float tv   = tr[tprev * 16 + tcur];
        const float scm  = (t == 0) ? 1.f : mk4;
        if (tcur == j) sc += (em4 + tv) * scm;   // fused path-score gather
        if (j == 0)    cnt += mk4;               // fused mask count

#pragma unroll
        for (int s = 0; s < 4; ++s) {
            const float um  = __shfl(mk4, s << 4);         // uniform mask_t
            const float emv = __shfl(em4, (s << 4) + j);   // em[t][j] -> all lanes
            if (um != 0.f) {
                const float eem = exp2f(fmaf(emv, L2E, -BIAS));
                BF4 A, B;
                A.u[0] = cvt_pk_bf16(eem * Ef[0], eem * Ef[1]);
                A.u[1] = cvt_pk_bf16(eem * Ef[2], eem * Ef[3]);
                B.u[0] = b01; B.u[1] = b23;
                f32x4 z = {0.f, 0.f, 0.f, 0.f};
                d = __builtin_amdgcn_mfma_f32_16x16x16bf16_1k(A.s, B.s, z, 0, 0, 0);
                b01 = cvt_pk_bf16(d[0], d[1]);   // D layout == B layout
                b23 = cvt_pk_bf16(d[2], d[3]);
            }
        }

        // ---- exact power-of-2 renorm every 32 steps (never on the last) ----
        if (((g + 4) & 31) == 0 && (g + 4) < LL) {
            float mm = fmaxf(fmaxf(d[0], d[1]), fmaxf(d[2], d[3]));
#pragma unroll
            for (int o = 1; o <= 32; o <<= 1) mm = fmaxf(mm, __shfl_xor(mm, o));
            if (mm > 0.f) {
                const int ex = (int)((__float_as_uint(mm) >> 23) & 0xFFu) - 127;
                const float s = __uint_as_float((unsigned)(127 - ex) << 23);
                e2f += (float)ex;
                b01 = cvt_pk_bf16(d[0] * s, d[1] * s);
                b23 = cvt_pk_bf16(d[2] * s, d[3] * s);
                d[0] *= s; d[1] *= s; d[2] *= s; d[3] *= s;
            }
        }
    }

    // ---- full-wave reductions of score and mask count ----
#pragma unroll
    for (int o = 1; o <= 32; o <<= 1) {
        sc  += __shfl_xor(sc, o);
        cnt += __shfl_xor(cnt, o);
    }

    // ---- alpha[row] = row-sums of product: sum d over the 16 j-lanes ----
    f32x4 a4 = d;
#pragma unroll
    for (int o = 1; o <= 8; o <<= 1) {
#pragma unroll
        for (int i = 0; i < 4; ++i) a4[i] += __shfl_xor(a4[i], o);
    }

    // ---- logsumexp over 16 rows (4 regs x 4 q-groups) ----
    const float base2 = e2f + BIAS * cnt;
    float yv[4], m2 = -1e38f;
#pragma unroll
    for (int i = 0; i < 4; ++i) {
        yv[i] = log2f(a4[i]) + base2 + Te[i] * L2E;   // log2f(0) = -inf ok
        m2 = fmaxf(m2, yv[i]);
    }
#pragma unroll
    for (int o = 16; o <= 32; o <<= 1) m2 = fmaxf(m2, __shfl_xor(m2, o));
    float e = 0.f;
#pragma unroll
    for (int i = 0; i < 4; ++i) e += exp2f(yv[i] - m2);
#pragma unroll
    for (int o = 16; o <= 32; o <<= 1) e += __shfl_xor(e, o);
    const float dp = (m2 + log2f(e)) * 0.69314718055994531f;

    // ---- per-batch result -> block reduce -> one atomic per block ----
    __shared__ float blk[NW];
    if (lane == 0) {
        const int  li = (int)cnt - 1;
        const long ti = base + li;
        const int  lt = tg[is64 ? (ti << 1) : ti];
        blk[wv] = dp - (sc + tr[lt * 16 + END_TAG]);
    }
    __syncthreads();
    if (threadIdx.x == 0) {
        float s = 0.f;
#pragma unroll
        for (int i = 0; i < NW; ++i) s += blk[i];
        atomicAdd(out, s);
    }
}

extern "C" void kernel_launch(void* const* d_in, const int* in_sizes, int n_in,
                              void* d_out, int out_size, void* d_ws, size_t ws_size,
                              hipStream_t stream) {
    const float* em = (const float*)d_in[0];
    const int*   tg = (const int*)d_in[1];
    const float* mk = (const float*)d_in[2];
    const float* tr = (const float*)d_in[3];
    float* out = (float*)d_out;

    hipMemsetAsync(out, 0, sizeof(float), stream);   // graph-capturable
    crf_fused<<<BS / NW, NW * 64, 0, stream>>>(em, tg, mk, tr, out);
}

// Round 4
// 116.028 us; speedup vs baseline: 1.3378x; 1.3378x over previous
//
#include <hip/hip_runtime.h>

#define BS 4096
#define LL 512
#define START_TAG 1
#define END_TAG 2
#define BIASF 4.75f
#define L2E 1.44269504f

typedef float f32x4 __attribute__((ext_vector_type(4)));
typedef short s16x4 __attribute__((ext_vector_type(4)));
union BF4 { unsigned u[2]; s16x4 s; };

__device__ __forceinline__ unsigned cvt_pk_bf16(float lo, float hi) {
    unsigned r;
    asm("v_cvt_pk_bf16_f32 %0, %1, %2" : "=v"(r) : "v"(lo), "v"(hi));
    return r;
}
__device__ __forceinline__ float blo(unsigned u) { return __uint_as_float(u << 16); }
__device__ __forceinline__ float bhi(unsigned u) { return __uint_as_float(u & 0xFFFF0000u); }

// One wave = 16 batches. Exp-space vector recursion, batch dim = MFMA columns:
//   D = E^T * B   (A = E^T static bf16; B[k][c] = alpha_c[k], bf16)
//   B'[r][c] = D[r][c] * e^{em[b_c][t][r]} * 2^-BIASF   (per-column mask select)
// Lane (j = col/batch, q): owns rows 4q..4q+3 of column j for B and D.
// Score + mask-count fused. Power-of-2 renorm per column every 8 steps (exact).
__global__ __launch_bounds__(64) void crf_vec16(
    const float* __restrict__ em, const int* __restrict__ tg,
    const float* __restrict__ mk, const float* __restrict__ tr,
    float* __restrict__ out)
{
    const int lane = threadIdx.x;
    const int j = lane & 15, q = lane >> 4;
    const int b = blockIdx.x * 16 + j;

    __shared__ float str[256];
    *(f32x4*)(str + lane * 4) = *(const f32x4*)(tr + lane * 4);
    __syncthreads();

    // tags dtype detection (u64 view: 16 words all <16 => int64 layout)
    int is64 = 1;
    {
        const unsigned long long* t64 = (const unsigned long long*)tg;
#pragma unroll
        for (int i = 0; i < 16; ++i) is64 &= (t64[i] < 16ull) ? 1 : 0;
    }

    // Static A = E^T: lane (j,q) holds A[row=j][k=4q+i] = E[4q+i][j] = exp(tr[4q+i][j])
    float Te[4];
    BF4 A;
    {
        float Ef[4];
#pragma unroll
        for (int i = 0; i < 4; ++i) {
            Ef[i] = expf(str[(q * 4 + i) * 16 + j]);   // exp(-1000) -> exact 0
            Te[i] = str[(q * 4 + i) * 16 + END_TAG];
        }
        A.u[0] = cvt_pk_bf16(Ef[0], Ef[1]);
        A.u[1] = cvt_pk_bf16(Ef[2], Ef[3]);
    }

    // State: B fragment (bf16 packed), init alpha = exp(0) = 1 for all rows
    unsigned p01 = 0x3F803F80u, p23 = 0x3F803F80u;
    float e2f = 0.f, cnt = 0.f, sc = 0.f;
    int tprev = START_TAG;

    const float* emp = em + ((long)b << 13) + (q << 2);  // em[b][t][4q..]
    const float* mkp = mk + ((long)b << 9);
    const int esz = is64 ? 2 : 1;
    const int* tgp = tg + (long)b * LL * esz;

    auto STEP = [&](int t, f32x4 ev, float um, int tcur) {
        const float e0 = exp2f(fmaf(ev.x, L2E, -BIASF));
        const float e1 = exp2f(fmaf(ev.y, L2E, -BIASF));
        const float e2 = exp2f(fmaf(ev.z, L2E, -BIASF));
        const float e3 = exp2f(fmaf(ev.w, L2E, -BIASF));
        BF4 Bp; Bp.u[0] = p01; Bp.u[1] = p23;
        f32x4 z = {0.f, 0.f, 0.f, 0.f};
        f32x4 d = __builtin_amdgcn_mfma_f32_16x16x16bf16_1k(A.s, Bp.s, z, 0, 0, 0);
        const unsigned n01 = cvt_pk_bf16(d[0] * e0, d[1] * e1);
        const unsigned n23 = cvt_pk_bf16(d[2] * e2, d[3] * e3);
        const bool up = um > 0.f;                  // per-column mask select
        p01 = up ? n01 : p01;
        p23 = up ? n23 : p23;
        cnt += um;
        // fused path score (this column's tag sequence; exactly one q matches)
        const float scm = (t == 0) ? 1.f : um;
        const int   tpv = (t == 0) ? START_TAG : tprev;
        const float tv  = str[tpv * 16 + tcur];
        if ((tcur >> 2) == q) {
            const float es = (tcur & 2) ? ((tcur & 1) ? ev.w : ev.z)
                                        : ((tcur & 1) ? ev.y : ev.x);
            sc = fmaf(es + tv, scm, sc);
        }
        tprev = tcur;
    };

    auto RENORM = [&]() {    // exact power-of-2 per-column renorm
        const float v0 = blo(p01), v1 = bhi(p01), v2 = blo(p23), v3 = bhi(p23);
        float mm = fmaxf(fmaxf(v0, v1), fmaxf(v2, v3));
        mm = fmaxf(mm, __shfl_xor(mm, 16));
        mm = fmaxf(mm, __shfl_xor(mm, 32));
        if (mm > 0.f) {
            const int ex = (int)((__float_as_uint(mm) >> 23) & 0xFFu) - 127;
            const float s = __uint_as_float((unsigned)(127 - ex) << 23);
            e2f += (float)ex;
            p01 = cvt_pk_bf16(v0 * s, v1 * s);
            p23 = cvt_pk_bf16(v2 * s, v3 * s);
        }
    };

    // main loop: 64 groups of 8 steps, double-buffered register prefetch
    f32x4 eA[8], eB[8]; float mA[8], mB[8]; int tA[8], tB[8];
#pragma unroll
    for (int s2 = 0; s2 < 8; ++s2) {
        eA[s2] = *(const f32x4*)(emp + s2 * 16);
        mA[s2] = mkp[s2];
        tA[s2] = tgp[s2 * esz];
    }
    for (int G = 0; G < 64; G += 2) {
        const int o1 = (G + 1) * 8;
        {
#pragma unroll
            for (int s2 = 0; s2 < 8; ++s2) {
                eB[s2] = *(const f32x4*)(emp + (o1 + s2) * 16);
                mB[s2] = mkp[o1 + s2];
                tB[s2] = tgp[(o1 + s2) * esz];
            }
        }
#pragma unroll
        for (int s2 = 0; s2 < 8; ++s2) STEP(G * 8 + s2, eA[s2], mA[s2], tA[s2]);
        RENORM();
        const int o2 = (G + 2) * 8;
        if (G + 2 < 64) {
#pragma unroll
            for (int s2 = 0; s2 < 8; ++s2) {
                eA[s2] = *(const f32x4*)(emp + (o2 + s2) * 16);
                mA[s2] = mkp[o2 + s2];
                tA[s2] = tgp[(o2 + s2) * esz];
            }
        }
#pragma unroll
        for (int s2 = 0; s2 < 8; ++s2) STEP(o1 + s2, eB[s2], mB[s2], tB[s2]);
        if (G + 2 < 64) RENORM();
    }

    // ---- epilogue ----
    sc += __shfl_xor(sc, 16);          // q-partials of this column's score
    sc += __shfl_xor(sc, 32);

    const float v0 = blo(p01), v1 = bhi(p01), v2 = blo(p23), v3 = bhi(p23);
    const float b2 = e2f + BIASF * cnt;
    const float y0 = log2f(v0) + b2 + Te[0] * L2E;
    const float y1 = log2f(v1) + b2 + Te[1] * L2E;
    const float y2 = log2f(v2) + b2 + Te[2] * L2E;
    const float y3 = log2f(v3) + b2 + Te[3] * L2E;
    float m2 = fmaxf(fmaxf(y0, y1), fmaxf(y2, y3));
    m2 = fmaxf(m2, __shfl_xor(m2, 16));
    m2 = fmaxf(m2, __shfl_xor(m2, 32));
    m2 = fmaxf(m2, -1e30f);
    float ee = exp2f(y0 - m2) + exp2f(y1 - m2) + exp2f(y2 - m2) + exp2f(y3 - m2);
    ee += __shfl_xor(ee, 16);
    ee += __shfl_xor(ee, 32);
    const float dp = (m2 + log2f(ee)) * 0.69314718055994531f;

    float res = 0.f;
    if (q == 0) {
        const int li = (int)cnt - 1;
        const int lt = tgp[li * esz];
        res = dp - (sc + str[lt * 16 + END_TAG]);
    }
    res += __shfl_xor(res, 1);
    res += __shfl_xor(res, 2);
    res += __shfl_xor(res, 4);
    res += __shfl_xor(res, 8);
    if (lane == 0) atomicAdd(out, res);
}

extern "C" void kernel_launch(void* const* d_in, const int* in_sizes, int n_in,
                              void* d_out, int out_size, void* d_ws, size_t ws_size,
                              hipStream_t stream) {
    const float* em = (const float*)d_in[0];
    const int*   tg = (const int*)d_in[1];
    const float* mk = (const float*)d_in[2];
    const float* tr = (const float*)d_in[3];
    float* out = (float*)d_out;

    hipMemsetAsync(out, 0, sizeof(float), stream);
    crf_vec16<<<BS / 16, 64, 0, stream>>>(em, tg, mk, tr, out);
}